// Round 8
// baseline (7162.466 us; speedup 1.0000x reference)
//
#include <hip/hip_runtime.h>
#include <math.h>

#define BB 64
#define TT 512
#define DD 128
#define HH 512
#define NCOMP 128

typedef unsigned long long u64;

// 8 agent-coherent 4B loads, stride 256B (hA[k][b] f32), one clause.
#define LOAD8(d0,d1,d2,d3,d4,d5,d6,d7, ptr)                                   \
  asm volatile("global_load_dword %0, %8, off sc0 sc1\n\t"                    \
               "global_load_dword %1, %8, off offset:256 sc0 sc1\n\t"         \
               "global_load_dword %2, %8, off offset:512 sc0 sc1\n\t"         \
               "global_load_dword %3, %8, off offset:768 sc0 sc1\n\t"         \
               "global_load_dword %4, %8, off offset:1024 sc0 sc1\n\t"        \
               "global_load_dword %5, %8, off offset:1280 sc0 sc1\n\t"        \
               "global_load_dword %6, %8, off offset:1536 sc0 sc1\n\t"        \
               "global_load_dword %7, %8, off offset:1792 sc0 sc1"            \
               : "=v"(d0), "=v"(d1), "=v"(d2), "=v"(d3),                      \
                 "=v"(d4), "=v"(d5), "=v"(d6), "=v"(d7)                       \
               : "v"(ptr) : "memory")

// ---------------------------------------------------------------------------
// Pre-kernel: transpose U into utT[quad][k][16], r = jp*4 + g.
// ---------------------------------------------------------------------------
__global__ __launch_bounds__(256) void uT_kernel(
    const float* __restrict__ Ui_w, const float* __restrict__ Uf_w,
    const float* __restrict__ Uo_w, const float* __restrict__ Ug_w,
    float* __restrict__ utT)
{
    const int q = blockIdx.x;
    const int jj0 = q << 2;
    for (int k = threadIdx.x; k < HH; k += 256) {
        float v[16];
        #pragma unroll
        for (int r = 0; r < 16; ++r) {
            const int jp = r >> 2, g = r & 3;
            const float* U = (g == 0) ? Ui_w : (g == 1) ? Uf_w : (g == 2) ? Uo_w : Ug_w;
            v[r] = U[(size_t)(jj0 + jp) * HH + k];
        }
        float4* dst = (float4*)(utT + ((size_t)q * HH + k) * 16);
        dst[0] = make_float4(v[0], v[1], v[2], v[3]);
        dst[1] = make_float4(v[4], v[5], v[6], v[7]);
        dst[2] = make_float4(v[8], v[9], v[10], v[11]);
        dst[3] = make_float4(v[12], v[13], v[14], v[15]);
    }
}

// ---------------------------------------------------------------------------
// Phase A: x-projections. out[bt*HH + jj], bt = b*T + t.
// ---------------------------------------------------------------------------
__global__ __launch_bounds__(512) void xproj_kernel(
    const float* __restrict__ x,
    const float* __restrict__ Wi_w, const float* __restrict__ Wi_b,
    const float* __restrict__ Wf_w, const float* __restrict__ Wf_b,
    const float* __restrict__ Wo_w, const float* __restrict__ Wo_b,
    const float* __restrict__ Wg_w, const float* __restrict__ Wg_b,
    float* __restrict__ xi, float* __restrict__ xf,
    float* __restrict__ xo, float* __restrict__ xg)
{
    const int tid  = threadIdx.x;
    const int w    = tid >> 6;
    const int lane = tid & 63;
    const int g     = w >> 1;
    const int jhalf = w & 1;
    const int bt0   = blockIdx.x * 128;

    const float* W  = (g == 0) ? Wi_w : (g == 1) ? Wf_w : (g == 2) ? Wo_w : Wg_w;
    const float* Bv = (g == 0) ? Wi_b : (g == 1) ? Wf_b : (g == 2) ? Wo_b : Wg_b;
    float* out      = (g == 0) ? xi   : (g == 1) ? xf   : (g == 2) ? xo   : xg;

    for (int blk = 0; blk < 4; ++blk) {
        const int jj = jhalf * 256 + blk * 64 + lane;
        float4 wr[32];
        const float4* wsrc = (const float4*)(W + (size_t)jj * DD);
        #pragma unroll
        for (int i = 0; i < 32; ++i) wr[i] = wsrc[i];
        const float bias = Bv[jj];

        for (int bt = bt0; bt < bt0 + 128; ++bt) {
            const float4* xr = (const float4*)(x + (size_t)bt * DD);
            float acc = bias;
            #pragma unroll
            for (int i = 0; i < 32; ++i) {
                const float4 xv = xr[i];
                acc += xv.x * wr[i].x + xv.y * wr[i].y + xv.z * wr[i].z + xv.w * wr[i].w;
            }
            out[(size_t)bt * HH + jj] = acc;
        }
    }
}

// ---------------------------------------------------------------------------
// Unified persistent kernel: blocks [0,128) compute, [128,256) drain.
// Compute WG i: quad = ((i&7)<<4)|(i>>3), cols jj0..jj0+3, 8 waves (k-split).
// Drain WG 128+i: serves the same quad — writes outputs b-major, gathers
// xp(t+2) into a tagged mailbox, publishes dflag back-pressure.
// hA[2][HH][BB] f32 (flag-gated), pay[2][3][HH][BB] f32, xpm[2][4][HH][BB]
// u64 tagged, flags[2][HH] (truth: stored after producer vmcnt(0) drain).
// ---------------------------------------------------------------------------
__global__ __launch_bounds__(512, 2) void lstm_persist(
    const float* __restrict__ utT,
    const float* __restrict__ Ui_w, const float* __restrict__ Uf_w,
    const float* __restrict__ Ug_w,
    float* __restrict__ b_i, float* __restrict__ b_f,
    float* __restrict__ b_o, float* __restrict__ b_g,
    float* __restrict__ hAf, float* __restrict__ pay,
    u64*   __restrict__ xpm,
    int*   __restrict__ flags, int* __restrict__ dflag)
{
    __shared__ float red[2][8][16][64];   // 64 KB (compute only)

    const int tid  = threadIdx.x;
    const int bid  = blockIdx.x;
    const int lane = tid & 63;

    if (bid >= NCOMP) {
        // ================= drain path (wave 0 only) =================
        if (tid >= 64) return;
        const int i    = bid - NCOMP;
        const int quad = ((i & 7) << 4) | (i >> 3);
        const int jj0  = quad << 2;

        // prime xp(0), xp(1) into mailbox (tags 1, 2)
        #pragma unroll
        for (int u = 0; u < 2; ++u) {
            #pragma unroll
            for (int g = 0; g < 4; ++g) {
                const float* src = (g == 0) ? b_i : (g == 1) ? b_f : (g == 2) ? b_o : b_g;
                #pragma unroll
                for (int c = 0; c < 4; ++c) {
                    const float v = src[(size_t)lane * TT * HH + (size_t)u * HH + jj0 + c];
                    const u64 pk = ((u64)(u + 1) << 32) | (u64)__float_as_uint(v);
                    u64* dp = xpm + ((size_t)((u & 1) * 4 + g) * HH + jj0 + c) * 64 + lane;
                    asm volatile("global_store_dwordx2 %0, %1, off sc0 sc1"
                                 :: "v"(dp), "v"(pk) : "memory");
                }
            }
        }

        for (int s = 0; s < TT; ++s) {
            const int p2 = (s + 1) & 1;
            // poll truth flags for our 4 columns
            {
                const int* fb = &flags[p2 * HH + jj0];
                for (;;) {
                    const int fv = __hip_atomic_load(&fb[lane & 3], __ATOMIC_RELAXED,
                                                     __HIP_MEMORY_SCOPE_AGENT);
                    if (__all(fv >= s + 1)) break;
                    __builtin_amdgcn_s_sleep(8);
                }
            }
            float vh[4], vf[4], ve[4], vc[4];
            #pragma unroll
            for (int c = 0; c < 4; ++c) {
                vh[c] = __hip_atomic_load(&hAf[((size_t)p2 * HH + jj0 + c) * 64 + lane],
                                          __ATOMIC_RELAXED, __HIP_MEMORY_SCOPE_AGENT);
                vf[c] = __hip_atomic_load(&pay[((size_t)(p2 * 3 + 0) * HH + jj0 + c) * 64 + lane],
                                          __ATOMIC_RELAXED, __HIP_MEMORY_SCOPE_AGENT);
                ve[c] = __hip_atomic_load(&pay[((size_t)(p2 * 3 + 1) * HH + jj0 + c) * 64 + lane],
                                          __ATOMIC_RELAXED, __HIP_MEMORY_SCOPE_AGENT);
                vc[c] = __hip_atomic_load(&pay[((size_t)(p2 * 3 + 2) * HH + jj0 + c) * 64 + lane],
                                          __ATOMIC_RELAXED, __HIP_MEMORY_SCOPE_AGENT);
            }
            const size_t ob = (size_t)lane * TT * HH + (size_t)s * HH + jj0;
            *(float4*)(b_i + ob) = make_float4(vh[0], vh[1], vh[2], vh[3]);
            *(float4*)(b_f + ob) = make_float4(vf[0], vf[1], vf[2], vf[3]);
            *(float4*)(b_o + ob) = make_float4(ve[0], ve[1], ve[2], ve[3]);
            *(float4*)(b_g + ob) = make_float4(vc[0], vc[1], vc[2], vc[3]);

            if (s + 2 < TT) {
                #pragma unroll
                for (int g = 0; g < 4; ++g) {
                    const float* src = (g == 0) ? b_i : (g == 1) ? b_f : (g == 2) ? b_o : b_g;
                    #pragma unroll
                    for (int c = 0; c < 4; ++c) {
                        const float v = src[(size_t)lane * TT * HH + (size_t)(s + 2) * HH + jj0 + c];
                        const u64 pk = ((u64)(s + 3) << 32) | (u64)__float_as_uint(v);
                        u64* dp = xpm + ((size_t)((s & 1) * 4 + g) * HH + jj0 + c) * 64 + lane;
                        asm volatile("global_store_dwordx2 %0, %1, off sc0 sc1"
                                     :: "v"(dp), "v"(pk) : "memory");
                    }
                }
            }
            if (lane == 0)
                __hip_atomic_store(&dflag[quad], s + 1, __ATOMIC_RELAXED,
                                   __HIP_MEMORY_SCOPE_AGENT);
        }
        return;
    }

    // ================= compute path =================
    const int w    = tid >> 6;
    const int quad = ((bid & 7) << 4) | (bid >> 3);
    const int jj0  = quad << 2;
    const int k0   = w << 6;

    const unsigned uoff = (unsigned)__builtin_amdgcn_readfirstlane(k0 << 4);
    const float4* up4 = (const float4*)(utT + (size_t)quad * (HH * 16) + uoff);

    float creg = 0.f, uid = 0.f, ufd = 0.f, ugd = 0.f;
    const int jp = (w < 4) ? w : 0;
    const int jj = jj0 + jp;
    if (w < 4) {
        uid = Ui_w[(size_t)jj * HH + jj];
        ufd = Uf_w[(size_t)jj * HH + jj];
        ugd = Ug_w[(size_t)jj * HH + jj];
    }

    for (int t = 0; t < TT; ++t) {
        const int p  = t & 1;
        const int np = p ^ 1;

        // early issues (w<4): xp mailbox spec + dflag back-pressure
        u64 xv[4];
        int dfv = 0x7fffffff;
        if (w < 4) {
            #pragma unroll
            for (int g = 0; g < 4; ++g)
                xv[g] = __hip_atomic_load(&xpm[((size_t)(p * 4 + g) * HH + jj) * 64 + lane],
                                          __ATOMIC_RELAXED, __HIP_MEMORY_SCOPE_AGENT);
            dfv = __hip_atomic_load(&dflag[quad], __ATOMIC_RELAXED, __HIP_MEMORY_SCOPE_AGENT);
        }

        // ---- poll truth flags for this wave's k-slice ----
        {
            const int* fb = &flags[p * HH + k0];
            for (;;) {
                const int fv = __hip_atomic_load(&fb[lane], __ATOMIC_RELAXED,
                                                 __HIP_MEMORY_SCOPE_AGENT);
                if (__all(fv >= t)) break;
                __builtin_amdgcn_s_sleep(1);
            }
        }

        // ---- clause: 64 x 4B in two 32-chunks, FMA-A overlaps chunk-B ----
        float hreg[64];
        const char* hp = (const char*)hAf + (size_t)(p * HH + k0) * 256 + lane * 4;
        LOAD8(hreg[0], hreg[1], hreg[2], hreg[3], hreg[4], hreg[5], hreg[6], hreg[7],  hp);
        LOAD8(hreg[8], hreg[9], hreg[10],hreg[11],hreg[12],hreg[13],hreg[14],hreg[15], hp + 2048);
        LOAD8(hreg[16],hreg[17],hreg[18],hreg[19],hreg[20],hreg[21],hreg[22],hreg[23], hp + 4096);
        LOAD8(hreg[24],hreg[25],hreg[26],hreg[27],hreg[28],hreg[29],hreg[30],hreg[31], hp + 6144);
        LOAD8(hreg[32],hreg[33],hreg[34],hreg[35],hreg[36],hreg[37],hreg[38],hreg[39], hp + 8192);
        LOAD8(hreg[40],hreg[41],hreg[42],hreg[43],hreg[44],hreg[45],hreg[46],hreg[47], hp + 10240);
        LOAD8(hreg[48],hreg[49],hreg[50],hreg[51],hreg[52],hreg[53],hreg[54],hreg[55], hp + 12288);
        LOAD8(hreg[56],hreg[57],hreg[58],hreg[59],hreg[60],hreg[61],hreg[62],hreg[63], hp + 14336);

        float acc[16];
        #pragma unroll
        for (int r = 0; r < 16; ++r) acc[r] = 0.f;

        asm volatile("s_waitcnt vmcnt(32)" ::: "memory");
        __builtin_amdgcn_sched_barrier(0);
        #pragma unroll
        for (int i = 0; i < 32; ++i) {
            const float4 u0 = up4[(i << 2) + 0];
            const float4 u1 = up4[(i << 2) + 1];
            const float4 u2 = up4[(i << 2) + 2];
            const float4 u3 = up4[(i << 2) + 3];
            const float hv = hreg[i];
            acc[0]  = fmaf(u0.x, hv, acc[0]);  acc[1]  = fmaf(u0.y, hv, acc[1]);
            acc[2]  = fmaf(u0.z, hv, acc[2]);  acc[3]  = fmaf(u0.w, hv, acc[3]);
            acc[4]  = fmaf(u1.x, hv, acc[4]);  acc[5]  = fmaf(u1.y, hv, acc[5]);
            acc[6]  = fmaf(u1.z, hv, acc[6]);  acc[7]  = fmaf(u1.w, hv, acc[7]);
            acc[8]  = fmaf(u2.x, hv, acc[8]);  acc[9]  = fmaf(u2.y, hv, acc[9]);
            acc[10] = fmaf(u2.z, hv, acc[10]); acc[11] = fmaf(u2.w, hv, acc[11]);
            acc[12] = fmaf(u3.x, hv, acc[12]); acc[13] = fmaf(u3.y, hv, acc[13]);
            acc[14] = fmaf(u3.z, hv, acc[14]); acc[15] = fmaf(u3.w, hv, acc[15]);
        }
        asm volatile("s_waitcnt vmcnt(0)" ::: "memory");
        __builtin_amdgcn_sched_barrier(0);
        #pragma unroll
        for (int i = 32; i < 64; ++i) {
            const float4 u0 = up4[(i << 2) + 0];
            const float4 u1 = up4[(i << 2) + 1];
            const float4 u2 = up4[(i << 2) + 2];
            const float4 u3 = up4[(i << 2) + 3];
            const float hv = hreg[i];
            acc[0]  = fmaf(u0.x, hv, acc[0]);  acc[1]  = fmaf(u0.y, hv, acc[1]);
            acc[2]  = fmaf(u0.z, hv, acc[2]);  acc[3]  = fmaf(u0.w, hv, acc[3]);
            acc[4]  = fmaf(u1.x, hv, acc[4]);  acc[5]  = fmaf(u1.y, hv, acc[5]);
            acc[6]  = fmaf(u1.z, hv, acc[6]);  acc[7]  = fmaf(u1.w, hv, acc[7]);
            acc[8]  = fmaf(u2.x, hv, acc[8]);  acc[9]  = fmaf(u2.y, hv, acc[9]);
            acc[10] = fmaf(u2.z, hv, acc[10]); acc[11] = fmaf(u2.w, hv, acc[11]);
            acc[12] = fmaf(u3.x, hv, acc[12]); acc[13] = fmaf(u3.y, hv, acc[13]);
            acc[14] = fmaf(u3.z, hv, acc[14]); acc[15] = fmaf(u3.w, hv, acc[15]);
        }

        #pragma unroll
        for (int r = 0; r < 16; ++r) red[p][w][r][lane] = acc[r];
        __syncthreads();

        if (w < 4) {
            float pre[4];
            #pragma unroll
            for (int g = 0; g < 4; ++g) {
                float s = 0.f;
                #pragma unroll
                for (int wk = 0; wk < 8; ++wk) s += red[p][wk][(jp << 2) + g][lane];
                pre[g] = s;
            }
            // xp verify (tags; published a step ahead -> near-always pass)
            for (;;) {
                bool ok = true;
                #pragma unroll
                for (int g = 0; g < 4; ++g)
                    ok = ok && ((int)(unsigned)(xv[g] >> 32) >= t + 1);
                if (__all(ok)) break;
                __builtin_amdgcn_s_sleep(2);
                #pragma unroll
                for (int g = 0; g < 4; ++g)
                    xv[g] = __hip_atomic_load(&xpm[((size_t)(p * 4 + g) * HH + jj) * 64 + lane],
                                              __ATOMIC_RELAXED, __HIP_MEMORY_SCOPE_AGENT);
            }
            const float pi = __uint_as_float((unsigned)xv[0]) + pre[0];
            const float pf = __uint_as_float((unsigned)xv[1]) + pre[1];
            const float po = __uint_as_float((unsigned)xv[2]) + pre[2];
            const float pg = __uint_as_float((unsigned)xv[3]) + pre[3];

            const float ig = __fdividef(1.f, 1.f + __expf(-pi));
            const float fg = __fdividef(1.f, 1.f + __expf(-pf));
            const float og = __fdividef(1.f, 1.f + __expf(-po));
            const float tg = __expf(-2.f * fmaxf(pg, -40.f));
            const float gg = __fdividef(1.f - tg, 1.f + tg);

            const float cp = creg;
            const float c  = fg * cp + ig * gg;
            creg = c;
            const float tc = __expf(-2.f * fmaxf(c, -40.f));
            const float th = __fdividef(1.f - tc, 1.f + tc);
            const float h  = og * th;
            const float e  = og * (1.f - th * th);
            const float cd = cp * (fg * (1.f - fg)) * ufd
                           + ig * (1.f - gg * gg) * ugd
                           + gg * (ig * (1.f - ig)) * uid;

            // back-pressure: drain must have finished step t-2 (dflag = s+1)
            while (dfv < t - 1) {
                __builtin_amdgcn_s_sleep(4);
                dfv = __hip_atomic_load(&dflag[quad], __ATOMIC_RELAXED,
                                        __HIP_MEMORY_SCOPE_AGENT);
            }

            // publish h + payload, drain, then truth flag
            {
                float* dh = hAf + ((size_t)np * HH + jj) * 64 + lane;
                float* df = pay + ((size_t)(np * 3 + 0) * HH + jj) * 64 + lane;
                float* de = pay + ((size_t)(np * 3 + 1) * HH + jj) * 64 + lane;
                float* dc = pay + ((size_t)(np * 3 + 2) * HH + jj) * 64 + lane;
                asm volatile("global_store_dword %0, %1, off sc0 sc1" :: "v"(dh), "v"(h)  : "memory");
                asm volatile("global_store_dword %0, %1, off sc0 sc1" :: "v"(df), "v"(fg) : "memory");
                asm volatile("global_store_dword %0, %1, off sc0 sc1" :: "v"(de), "v"(e)  : "memory");
                asm volatile("global_store_dword %0, %1, off sc0 sc1" :: "v"(dc), "v"(cd) : "memory");
                asm volatile("s_waitcnt vmcnt(0)" ::: "memory");
                if (lane == 0)
                    __hip_atomic_store(&flags[np * HH + jj], t + 1, __ATOMIC_RELAXED,
                                       __HIP_MEMORY_SCOPE_AGENT);
            }
        }
    }
}

// ys[r] = dot(hs[r,:], out_w) + out_b ; one wave per row r = b*T + t
__global__ __launch_bounds__(256) void lstm_y(
    const float* __restrict__ hs, const float* __restrict__ out_w,
    const float* __restrict__ out_b, float* __restrict__ ys)
{
    const int wave = threadIdx.x >> 6;
    const int lane = threadIdx.x & 63;
    const int r = blockIdx.x * 4 + wave;

    const float4* hv = (const float4*)(hs + (size_t)r * HH);
    const float4* wv = (const float4*)out_w;
    float acc = 0.f;
    #pragma unroll
    for (int i = 0; i < 2; ++i) {
        float4 h4 = hv[lane * 2 + i];
        float4 w4 = wv[lane * 2 + i];
        acc += h4.x * w4.x + h4.y * w4.y + h4.z * w4.z + h4.w * w4.w;
    }
    #pragma unroll
    for (int m = 32; m >= 1; m >>= 1) acc += __shfl_xor(acc, m, 64);
    if (lane == 0) ys[r] = acc + out_b[0];
}

extern "C" void kernel_launch(void* const* d_in, const int* in_sizes, int n_in,
                              void* d_out, int out_size, void* d_ws, size_t ws_size,
                              hipStream_t stream)
{
    const float* x    = (const float*)d_in[0];
    const float* Wi_w = (const float*)d_in[1];
    const float* Wi_b = (const float*)d_in[2];
    const float* Ui_w = (const float*)d_in[3];
    const float* Wf_w = (const float*)d_in[4];
    const float* Wf_b = (const float*)d_in[5];
    const float* Uf_w = (const float*)d_in[6];
    const float* Wo_w = (const float*)d_in[7];
    const float* Wo_b = (const float*)d_in[8];
    const float* Uo_w = (const float*)d_in[9];
    const float* Wg_w = (const float*)d_in[10];
    const float* Wg_b = (const float*)d_in[11];
    const float* Ug_w = (const float*)d_in[12];
    const float* out_w = (const float*)d_in[13];
    const float* out_b = (const float*)d_in[14];

    float* ys  = (float*)d_out;                     // [B*T]
    float* hs  = ys + (size_t)BB * TT;              // [B*T*H]
    float* fs  = hs + (size_t)BB * TT * HH;
    float* es  = fs + (size_t)BB * TT * HH;
    float* cds = es + (size_t)BB * TT * HH;

    // ws layout: [hAf 256K][pay 768K][xpm 2M][flags 4K][dflag 512B][utT 4M]
    float* hAf   = (float*)d_ws;                         // 2*HH*BB
    float* pay   = hAf + (size_t)2 * HH * BB;            // 2*3*HH*BB
    u64*   xpm   = (u64*)(pay + (size_t)6 * HH * BB);    // 2*4*HH*BB u64
    int*   flags = (int*)(xpm + (size_t)8 * HH * BB);    // 2*HH
    int*   dflag = flags + 2 * HH;                       // 128
    float* utT   = (float*)(dflag + 128);

    const size_t zbytes = (size_t)2 * HH * BB * 4 + (size_t)6 * HH * BB * 4
                        + (size_t)8 * HH * BB * 8 + (size_t)2 * HH * 4 + 128 * 4;
    hipMemsetAsync(d_ws, 0, zbytes, stream);

    uT_kernel<<<NCOMP, 256, 0, stream>>>(Ui_w, Uf_w, Uo_w, Ug_w, utT);

    xproj_kernel<<<256, 512, 0, stream>>>(x, Wi_w, Wi_b, Wf_w, Wf_b,
                                          Wo_w, Wo_b, Wg_w, Wg_b,
                                          hs, fs, es, cds);

    lstm_persist<<<256, 512, 0, stream>>>(utT, Ui_w, Uf_w, Ug_w,
                                          hs, fs, es, cds,
                                          hAf, pay, xpm, flags, dflag);

    lstm_y<<<(BB * TT) / 4, 256, 0, stream>>>(hs, out_w, out_b, ys);
}

// Round 9
// 6444.483 us; speedup vs baseline: 1.1114x; 1.1114x over previous
//
#include <hip/hip_runtime.h>
#include <math.h>

#define BB 64
#define TT 512
#define DD 128
#define HH 512
#define NWG 128
#define TAGM 511u

// 8 agent-coherent 4B loads, stride 256B (hA[k][b]), one indivisible clause.
#define LOAD8(d0,d1,d2,d3,d4,d5,d6,d7, ptr)                                   \
  asm volatile("global_load_dword %0, %8, off sc0 sc1\n\t"                    \
               "global_load_dword %1, %8, off offset:256 sc0 sc1\n\t"         \
               "global_load_dword %2, %8, off offset:512 sc0 sc1\n\t"         \
               "global_load_dword %3, %8, off offset:768 sc0 sc1\n\t"         \
               "global_load_dword %4, %8, off offset:1024 sc0 sc1\n\t"        \
               "global_load_dword %5, %8, off offset:1280 sc0 sc1\n\t"        \
               "global_load_dword %6, %8, off offset:1536 sc0 sc1\n\t"        \
               "global_load_dword %7, %8, off offset:1792 sc0 sc1"            \
               : "=v"(d0), "=v"(d1), "=v"(d2), "=v"(d3),                      \
                 "=v"(d4), "=v"(d5), "=v"(d6), "=v"(d7)                       \
               : "v"(ptr) : "memory")

// WG barrier ordering LDS only — global stores stay in flight across steps.
#define BARRIER_LGKM() asm volatile("s_waitcnt lgkmcnt(0)\n\ts_barrier" ::: "memory")

// ---------------------------------------------------------------------------
// Pre-kernel: transpose U into utT[quad][k][16], r = jp*4 + g.
// ---------------------------------------------------------------------------
__global__ __launch_bounds__(256) void uT_kernel(
    const float* __restrict__ Ui_w, const float* __restrict__ Uf_w,
    const float* __restrict__ Uo_w, const float* __restrict__ Ug_w,
    float* __restrict__ utT)
{
    const int q = blockIdx.x;
    const int jj0 = q << 2;
    for (int k = threadIdx.x; k < HH; k += 256) {
        float v[16];
        #pragma unroll
        for (int r = 0; r < 16; ++r) {
            const int jp = r >> 2, g = r & 3;
            const float* U = (g == 0) ? Ui_w : (g == 1) ? Uf_w : (g == 2) ? Uo_w : Ug_w;
            v[r] = U[(size_t)(jj0 + jp) * HH + k];
        }
        float4* dst = (float4*)(utT + ((size_t)q * HH + k) * 16);
        dst[0] = make_float4(v[0], v[1], v[2], v[3]);
        dst[1] = make_float4(v[4], v[5], v[6], v[7]);
        dst[2] = make_float4(v[8], v[9], v[10], v[11]);
        dst[3] = make_float4(v[12], v[13], v[14], v[15]);
    }
}

// ---------------------------------------------------------------------------
// Phase A: x-projections. out[bt*HH + jj], bt = b*T + t.
// ---------------------------------------------------------------------------
__global__ __launch_bounds__(512) void xproj_kernel(
    const float* __restrict__ x,
    const float* __restrict__ Wi_w, const float* __restrict__ Wi_b,
    const float* __restrict__ Wf_w, const float* __restrict__ Wf_b,
    const float* __restrict__ Wo_w, const float* __restrict__ Wo_b,
    const float* __restrict__ Wg_w, const float* __restrict__ Wg_b,
    float* __restrict__ xi, float* __restrict__ xf,
    float* __restrict__ xo, float* __restrict__ xg)
{
    const int tid  = threadIdx.x;
    const int w    = tid >> 6;
    const int lane = tid & 63;
    const int g     = w >> 1;
    const int jhalf = w & 1;
    const int bt0   = blockIdx.x * 128;

    const float* W  = (g == 0) ? Wi_w : (g == 1) ? Wf_w : (g == 2) ? Wo_w : Wg_w;
    const float* Bv = (g == 0) ? Wi_b : (g == 1) ? Wf_b : (g == 2) ? Wo_b : Wg_b;
    float* out      = (g == 0) ? xi   : (g == 1) ? xf   : (g == 2) ? xo   : xg;

    for (int blk = 0; blk < 4; ++blk) {
        const int jj = jhalf * 256 + blk * 64 + lane;
        float4 wr[32];
        const float4* wsrc = (const float4*)(W + (size_t)jj * DD);
        #pragma unroll
        for (int i = 0; i < 32; ++i) wr[i] = wsrc[i];
        const float bias = Bv[jj];

        for (int bt = bt0; bt < bt0 + 128; ++bt) {
            const float4* xr = (const float4*)(x + (size_t)bt * DD);
            float acc = bias;
            #pragma unroll
            for (int i = 0; i < 32; ++i) {
                const float4 xv = xr[i];
                acc += xv.x * wr[i].x + xv.y * wr[i].y + xv.z * wr[i].z + xv.w * wr[i].w;
            }
            out[(size_t)bt * HH + jj] = acc;
        }
    }
}

// ---------------------------------------------------------------------------
// Persistent recurrence. Mantissa-tagged h (9 LSBs = gen mod 512): publish
// needs NO drain; flags are coalesced hints; tags are the correctness gate.
// lgkm-only barriers keep global stores in flight across steps.
// 128 WGs x 512 thr. WG owns quad = ((wg&7)<<4)|(wg>>3), jj0 = quad*4.
// Wave w covers k in [w*64, w*64+64). hA[2][HH][BB] u32, flags[2][HH].
// ---------------------------------------------------------------------------
__global__ __launch_bounds__(512, 2) void lstm_persist(
    const float* __restrict__ utT,
    const float* __restrict__ Ui_w, const float* __restrict__ Uf_w,
    const float* __restrict__ Ug_w,
    float* __restrict__ b_i, float* __restrict__ b_f,   // xi->hs, xf->fs
    float* __restrict__ b_o, float* __restrict__ b_g,   // xo->es, xg->cds
    unsigned* __restrict__ hA,    // [2][HH][BB] tagged f32
    int* __restrict__ flags)      // [2][HH]
{
    __shared__ float red[2][8][16][64];   // 64 KB, parity-double-buffered
    __shared__ float sh[2][4][64][4];     // 8 KB  [parity][arr][b][jp]
    __shared__ float xps[2][4][4][64];    // 8 KB  [parity][gate][jp][b]

    const int tid  = threadIdx.x;
    const int w    = tid >> 6;
    const int lane = tid & 63;
    const int wg   = blockIdx.x;
    const int quad = ((wg & 7) << 4) | (wg >> 3);
    const int jj0  = quad << 2;
    const int k0   = w << 6;

    const unsigned uoff = (unsigned)__builtin_amdgcn_readfirstlane(k0 << 4);
    const float4* up4 = (const float4*)(utT + (size_t)quad * (HH * 16) + uoff);

    float creg = 0.f, uid = 0.f, ufd = 0.f, ugd = 0.f;
    const int jp = (w < 4) ? w : 0;
    const int jj = jj0 + jp;
    if (w < 4) {
        uid = Ui_w[(size_t)jj * HH + jj];
        ufd = Uf_w[(size_t)jj * HH + jj];
        ugd = Ug_w[(size_t)jj * HH + jj];
        // prime xp(0) into LDS (one-time scattered loads)
        const size_t a0 = (size_t)lane * TT * HH + jj;
        xps[0][0][w][lane] = b_i[a0];
        xps[0][1][w][lane] = b_f[a0];
        xps[0][2][w][lane] = b_o[a0];
        xps[0][3][w][lane] = b_g[a0];
    }
    __syncthreads();

    for (int t = 0; t < TT; ++t) {
        const int p  = t & 1;
        const int np = p ^ 1;
        const unsigned tgt = (unsigned)t & TAGM;

        // ---- coalesced flag-hint poll (4 lines) ----
        {
            const int* fb = &flags[p * HH + k0];
            for (;;) {
                const int fv = __hip_atomic_load(&fb[lane], __ATOMIC_RELAXED,
                                                 __HIP_MEMORY_SCOPE_AGENT);
                if (__all(fv >= t)) break;
                __builtin_amdgcn_s_sleep(2);
            }
        }

        // ---- tagged clause; tag-verify fused into FMA; rare full retry ----
        unsigned hv[64];
        float acc[16];
        const char* hp = (const char*)hA + ((size_t)p * HH + k0) * 256 + lane * 4;
        for (;;) {
            LOAD8(hv[0], hv[1], hv[2], hv[3], hv[4], hv[5], hv[6], hv[7],  hp);
            LOAD8(hv[8], hv[9], hv[10],hv[11],hv[12],hv[13],hv[14],hv[15], hp + 2048);
            LOAD8(hv[16],hv[17],hv[18],hv[19],hv[20],hv[21],hv[22],hv[23], hp + 4096);
            LOAD8(hv[24],hv[25],hv[26],hv[27],hv[28],hv[29],hv[30],hv[31], hp + 6144);
            LOAD8(hv[32],hv[33],hv[34],hv[35],hv[36],hv[37],hv[38],hv[39], hp + 8192);
            LOAD8(hv[40],hv[41],hv[42],hv[43],hv[44],hv[45],hv[46],hv[47], hp + 10240);
            LOAD8(hv[48],hv[49],hv[50],hv[51],hv[52],hv[53],hv[54],hv[55], hp + 12288);
            LOAD8(hv[56],hv[57],hv[58],hv[59],hv[60],hv[61],hv[62],hv[63], hp + 14336);

            #pragma unroll
            for (int r = 0; r < 16; ++r) acc[r] = 0.f;
            unsigned bad = 0;

            asm volatile("s_waitcnt vmcnt(32)" ::: "memory");
            __builtin_amdgcn_sched_barrier(0);
            #pragma unroll
            for (int i = 0; i < 32; ++i) {
                const float4 u0 = up4[(i << 2) + 0];
                const float4 u1 = up4[(i << 2) + 1];
                const float4 u2 = up4[(i << 2) + 2];
                const float4 u3 = up4[(i << 2) + 3];
                bad |= (hv[i] ^ tgt) & TAGM;
                const float hvf = __uint_as_float(hv[i] & ~TAGM);
                acc[0]  = fmaf(u0.x, hvf, acc[0]);  acc[1]  = fmaf(u0.y, hvf, acc[1]);
                acc[2]  = fmaf(u0.z, hvf, acc[2]);  acc[3]  = fmaf(u0.w, hvf, acc[3]);
                acc[4]  = fmaf(u1.x, hvf, acc[4]);  acc[5]  = fmaf(u1.y, hvf, acc[5]);
                acc[6]  = fmaf(u1.z, hvf, acc[6]);  acc[7]  = fmaf(u1.w, hvf, acc[7]);
                acc[8]  = fmaf(u2.x, hvf, acc[8]);  acc[9]  = fmaf(u2.y, hvf, acc[9]);
                acc[10] = fmaf(u2.z, hvf, acc[10]); acc[11] = fmaf(u2.w, hvf, acc[11]);
                acc[12] = fmaf(u3.x, hvf, acc[12]); acc[13] = fmaf(u3.y, hvf, acc[13]);
                acc[14] = fmaf(u3.z, hvf, acc[14]); acc[15] = fmaf(u3.w, hvf, acc[15]);
            }
            asm volatile("s_waitcnt vmcnt(0)" ::: "memory");
            __builtin_amdgcn_sched_barrier(0);
            #pragma unroll
            for (int i = 32; i < 64; ++i) {
                const float4 u0 = up4[(i << 2) + 0];
                const float4 u1 = up4[(i << 2) + 1];
                const float4 u2 = up4[(i << 2) + 2];
                const float4 u3 = up4[(i << 2) + 3];
                bad |= (hv[i] ^ tgt) & TAGM;
                const float hvf = __uint_as_float(hv[i] & ~TAGM);
                acc[0]  = fmaf(u0.x, hvf, acc[0]);  acc[1]  = fmaf(u0.y, hvf, acc[1]);
                acc[2]  = fmaf(u0.z, hvf, acc[2]);  acc[3]  = fmaf(u0.w, hvf, acc[3]);
                acc[4]  = fmaf(u1.x, hvf, acc[4]);  acc[5]  = fmaf(u1.y, hvf, acc[5]);
                acc[6]  = fmaf(u1.z, hvf, acc[6]);  acc[7]  = fmaf(u1.w, hvf, acc[7]);
                acc[8]  = fmaf(u2.x, hvf, acc[8]);  acc[9]  = fmaf(u2.y, hvf, acc[9]);
                acc[10] = fmaf(u2.z, hvf, acc[10]); acc[11] = fmaf(u2.w, hvf, acc[11]);
                acc[12] = fmaf(u3.x, hvf, acc[12]); acc[13] = fmaf(u3.y, hvf, acc[13]);
                acc[14] = fmaf(u3.z, hvf, acc[14]); acc[15] = fmaf(u3.w, hvf, acc[15]);
            }
            if (__all(bad == 0)) break;

            // rare straggler: wait on flags, then reload whole clause
            const int* fb = &flags[p * HH + k0];
            for (;;) {
                const int fv = __hip_atomic_load(&fb[lane], __ATOMIC_RELAXED,
                                                 __HIP_MEMORY_SCOPE_AGENT);
                if (__all(fv >= t)) break;
                __builtin_amdgcn_s_sleep(2);
            }
        }

        #pragma unroll
        for (int r = 0; r < 16; ++r) red[p][w][r][lane] = acc[r];
        BARRIER_LGKM();

        if (w < 4) {
            float pre[4];
            #pragma unroll
            for (int g = 0; g < 4; ++g) {
                float s = 0.f;
                #pragma unroll
                for (int wk = 0; wk < 8; ++wk) s += red[p][wk][(jp << 2) + g][lane];
                pre[g] = s;
            }
            const float pi = xps[p][0][jp][lane] + pre[0];
            const float pf = xps[p][1][jp][lane] + pre[1];
            const float po = xps[p][2][jp][lane] + pre[2];
            const float pg = xps[p][3][jp][lane] + pre[3];

            const float ig = __fdividef(1.f, 1.f + __expf(-pi));
            const float fg = __fdividef(1.f, 1.f + __expf(-pf));
            const float og = __fdividef(1.f, 1.f + __expf(-po));
            const float tg = __expf(-2.f * fmaxf(pg, -40.f));
            const float gg = __fdividef(1.f - tg, 1.f + tg);

            const float cp = creg;
            const float c  = fg * cp + ig * gg;
            creg = c;
            const float tc = __expf(-2.f * fmaxf(c, -40.f));
            const float th = __fdividef(1.f - tc, 1.f + tc);
            const float h  = og * th;
            const float e  = og * (1.f - th * th);
            const float cd = cp * (fg * (1.f - fg)) * ufd
                           + ig * (1.f - gg * gg) * ugd
                           + gg * (ig * (1.f - ig)) * uid;

            // publish tagged h + flag hint — NO drain anywhere
            {
                const unsigned pk = (__float_as_uint(h) & ~TAGM)
                                  | ((unsigned)(t + 1) & TAGM);
                unsigned* dp = hA + ((size_t)np * HH + jj) * 64 + lane;
                asm volatile("global_store_dword %0, %1, off sc0 sc1"
                             :: "v"(dp), "v"(pk) : "memory");
                if (lane == 0)
                    __hip_atomic_store(&flags[np * HH + jj], t + 1,
                                       __ATOMIC_RELAXED, __HIP_MEMORY_SCOPE_AGENT);
            }

            // stage outputs (full-precision h) for deferred drain
            sh[p][0][lane][w] = h;
            sh[p][1][lane][w] = fg;
            sh[p][2][lane][w] = e;
            sh[p][3][lane][w] = cd;
        } else {
            const int w4 = w - 4;
            if (t > 0) {
                float* base = (w4 == 0) ? b_i : (w4 == 1) ? b_f : (w4 == 2) ? b_o : b_g;
                const float4 v = *(const float4*)&sh[np][w4][lane][0];
                *(float4*)(base + (size_t)lane * TT * HH + (size_t)(t - 1) * HH + jj0) = v;
            }
            if (t + 1 < TT) {
                const size_t ap = (size_t)lane * TT * HH + (size_t)(t + 1) * HH + (jj0 + w4);
                xps[np][0][w4][lane] = b_i[ap];
                xps[np][1][w4][lane] = b_f[ap];
                xps[np][2][w4][lane] = b_o[ap];
                xps[np][3][w4][lane] = b_g[ap];
            }
        }
    }

    // drain final step's outputs (gen TT-1 lives in sh[1])
    __syncthreads();
    if (w >= 4) {
        const int arr = (tid - 256) >> 6;
        float* base = (arr == 0) ? b_i : (arr == 1) ? b_f : (arr == 2) ? b_o : b_g;
        const float4 v = *(const float4*)&sh[1][arr][lane][0];
        *(float4*)(base + (size_t)lane * TT * HH + (size_t)(TT - 1) * HH + jj0) = v;
    }
}

// ys[r] = dot(hs[r,:], out_w) + out_b ; one wave per row r = b*T + t
__global__ __launch_bounds__(256) void lstm_y(
    const float* __restrict__ hs, const float* __restrict__ out_w,
    const float* __restrict__ out_b, float* __restrict__ ys)
{
    const int wave = threadIdx.x >> 6;
    const int lane = threadIdx.x & 63;
    const int r = blockIdx.x * 4 + wave;

    const float4* hv = (const float4*)(hs + (size_t)r * HH);
    const float4* wv = (const float4*)out_w;
    float acc = 0.f;
    #pragma unroll
    for (int i = 0; i < 2; ++i) {
        float4 h4 = hv[lane * 2 + i];
        float4 w4 = wv[lane * 2 + i];
        acc += h4.x * w4.x + h4.y * w4.y + h4.z * w4.z + h4.w * w4.w;
    }
    #pragma unroll
    for (int m = 32; m >= 1; m >>= 1) acc += __shfl_xor(acc, m, 64);
    if (lane == 0) ys[r] = acc + out_b[0];
}

extern "C" void kernel_launch(void* const* d_in, const int* in_sizes, int n_in,
                              void* d_out, int out_size, void* d_ws, size_t ws_size,
                              hipStream_t stream)
{
    const float* x    = (const float*)d_in[0];
    const float* Wi_w = (const float*)d_in[1];
    const float* Wi_b = (const float*)d_in[2];
    const float* Ui_w = (const float*)d_in[3];
    const float* Wf_w = (const float*)d_in[4];
    const float* Wf_b = (const float*)d_in[5];
    const float* Uf_w = (const float*)d_in[6];
    const float* Wo_w = (const float*)d_in[7];
    const float* Wo_b = (const float*)d_in[8];
    const float* Uo_w = (const float*)d_in[9];
    const float* Wg_w = (const float*)d_in[10];
    const float* Wg_b = (const float*)d_in[11];
    const float* Ug_w = (const float*)d_in[12];
    const float* out_w = (const float*)d_in[13];
    const float* out_b = (const float*)d_in[14];

    float* ys  = (float*)d_out;                     // [B*T]
    float* hs  = ys + (size_t)BB * TT;              // [B*T*H]
    float* fs  = hs + (size_t)BB * TT * HH;
    float* es  = fs + (size_t)BB * TT * HH;
    float* cds = es + (size_t)BB * TT * HH;

    // ws layout: [hA 256KB][flags 4KB][utT 4MB]
    unsigned* hA    = (unsigned*)d_ws;
    int*      flags = (int*)(hA + (size_t)2 * HH * BB);
    float*    utT   = (float*)(flags + 2 * HH);

    // zero hA (tag=0 == t=0, h=0) + flags every call (graph-replay safe)
    hipMemsetAsync(d_ws, 0,
                   (size_t)2 * HH * BB * sizeof(unsigned)
                   + (size_t)2 * HH * sizeof(int), stream);

    uT_kernel<<<NWG, 256, 0, stream>>>(Ui_w, Uf_w, Uo_w, Ug_w, utT);

    xproj_kernel<<<256, 512, 0, stream>>>(x, Wi_w, Wi_b, Wf_w, Wf_b,
                                          Wo_w, Wo_b, Wg_w, Wg_b,
                                          hs, fs, es, cds);

    lstm_persist<<<NWG, 512, 0, stream>>>(utT, Ui_w, Uf_w, Ug_w,
                                          hs, fs, es, cds, hA, flags);

    lstm_y<<<(BB * TT) / 4, 256, 0, stream>>>(hs, out_w, out_b, ys);
}

// Round 10
// 3684.868 us; speedup vs baseline: 1.9438x; 1.7489x over previous
//
#include <hip/hip_runtime.h>
#include <math.h>

#define BB 64
#define TT 512
#define DD 128
#define HH 512
#define NROW 8
#define NCG 16
#define NWG (NROW * NCG)   // 128
#define TAGM 511u

// two agent-coherent 4B loads, stride 2048B (adjacent batches in hpub)
#define LOADP(d0,d1,ptr)                                                      \
  asm volatile("global_load_dword %0, %2, off sc0 sc1\n\t"                    \
               "global_load_dword %1, %2, off offset:2048 sc0 sc1"            \
               : "=v"(d0), "=v"(d1) : "v"(ptr) : "memory")

// WG barrier ordering LDS only — global stores stay in flight across steps.
#define BARRIER_LGKM() asm volatile("s_waitcnt lgkmcnt(0)\n\ts_barrier" ::: "memory")

// ---------------------------------------------------------------------------
// Pre-kernel: utT2[cg][k][128], inner = 2*l + d -> U_g[cg*32 + (l&31)][k],
// g = (l>>5)*2 + d. Feeds register-resident per-lane U (float2 per k).
// ---------------------------------------------------------------------------
__global__ __launch_bounds__(256) void uT2_kernel(
    const float* __restrict__ Ui_w, const float* __restrict__ Uf_w,
    const float* __restrict__ Uo_w, const float* __restrict__ Ug_w,
    float* __restrict__ utT2)
{
    const int cg = blockIdx.x;
    for (int idx = threadIdx.x; idx < HH * 128; idx += 256) {
        const int k = idx >> 7, ii = idx & 127;
        const int l = ii >> 1, d = ii & 1;
        const int j = cg * 32 + (l & 31);
        const int g = ((l >> 5) << 1) + d;
        const float* U = (g == 0) ? Ui_w : (g == 1) ? Uf_w : (g == 2) ? Uo_w : Ug_w;
        utT2[((size_t)cg * HH + k) * 128 + ii] = U[(size_t)j * HH + k];
    }
}

// ---------------------------------------------------------------------------
// Phase A: x-projections. out[bt*HH + jj], bt = b*T + t.
// ---------------------------------------------------------------------------
__global__ __launch_bounds__(512) void xproj_kernel(
    const float* __restrict__ x,
    const float* __restrict__ Wi_w, const float* __restrict__ Wi_b,
    const float* __restrict__ Wf_w, const float* __restrict__ Wf_b,
    const float* __restrict__ Wo_w, const float* __restrict__ Wo_b,
    const float* __restrict__ Wg_w, const float* __restrict__ Wg_b,
    float* __restrict__ xi, float* __restrict__ xf,
    float* __restrict__ xo, float* __restrict__ xg)
{
    const int tid  = threadIdx.x;
    const int w    = tid >> 6;
    const int lane = tid & 63;
    const int g     = w >> 1;
    const int jhalf = w & 1;
    const int bt0   = blockIdx.x * 128;

    const float* W  = (g == 0) ? Wi_w : (g == 1) ? Wf_w : (g == 2) ? Wo_w : Wg_w;
    const float* Bv = (g == 0) ? Wi_b : (g == 1) ? Wf_b : (g == 2) ? Wo_b : Wg_b;
    float* out      = (g == 0) ? xi   : (g == 1) ? xf   : (g == 2) ? xo   : xg;

    for (int blk = 0; blk < 4; ++blk) {
        const int jj = jhalf * 256 + blk * 64 + lane;
        float4 wr[32];
        const float4* wsrc = (const float4*)(W + (size_t)jj * DD);
        #pragma unroll
        for (int i = 0; i < 32; ++i) wr[i] = wsrc[i];
        const float bias = Bv[jj];

        for (int bt = bt0; bt < bt0 + 128; ++bt) {
            const float4* xr = (const float4*)(x + (size_t)bt * DD);
            float acc = bias;
            #pragma unroll
            for (int i = 0; i < 32; ++i) {
                const float4 xv = xr[i];
                acc += xv.x * wr[i].x + xv.y * wr[i].y + xv.z * wr[i].z + xv.w * wr[i].w;
            }
            out[(size_t)bt * HH + jj] = acc;
        }
    }
}

// ---------------------------------------------------------------------------
// Persistent recurrence, batch-row-split. WG (row r = wg&7, cgroup cg = wg>>3)
// owns batches [8r, 8r+8) x cols [32cg, 32cg+32) x 4 gates. Communication
// only within the 16 WGs of a row (same XCD under %8 dispatch heuristic).
// Wave w: k-slice [64w, 64w+64); U slice register-resident (u2[64] float2).
// hpub[2][64][512] mantissa-tagged u32 (9 LSBs = gen mod 512), no drains.
// flags[2][8][16] coalesced hints (one line per row). 2 lgkm barriers/step.
// ---------------------------------------------------------------------------
__global__ __launch_bounds__(512, 2) void lstm_persist(
    const float* __restrict__ utT2,
    const float* __restrict__ Ui_w, const float* __restrict__ Uf_w,
    const float* __restrict__ Ug_w,
    float* __restrict__ b_i, float* __restrict__ b_f,   // xi->hs, xf->fs
    float* __restrict__ b_o, float* __restrict__ b_g,   // xo->es, xg->cds
    unsigned* __restrict__ hpub,   // [2][64][512]
    int* __restrict__ flags)       // [2][8][16]
{
    __shared__ float hlds[8][8][64];     // 16 KB [wave][b][k]
    __shared__ float red[8][1024];       // 32 KB [wave][(b*32+col)*4+g]
    __shared__ float pre[1024];          //  4 KB
    __shared__ float shout[2][4][256];   //  8 KB [parity][arr][b*32+col]
    __shared__ float xps[2][4][256];     //  8 KB [parity][gate][b*32+col]

    const int tid  = threadIdx.x;
    const int w    = tid >> 6;
    const int lane = tid & 63;
    const int wg   = blockIdx.x;
    const int r    = wg & 7;
    const int cg   = wg >> 3;
    const int k0   = w << 6;

    // register-resident U slice: lane owns (col=lane&31, gates g0,g0+1), 64 k
    float2 u2[64];
    {
        const float* ub = utT2 + ((size_t)cg * HH + k0) * 128 + 2 * lane;
        #pragma unroll
        for (int k = 0; k < 64; ++k) u2[k] = *(const float2*)(ub + (size_t)k * 128);
    }

    // pointwise state (threads 0..255): thread = (b = tid>>5, col = tid&31)
    float creg = 0.f, uid = 0.f, ufd = 0.f, ugd = 0.f;
    int jjg = 0, gb = 0;
    if (tid < 256) {
        const int pb = tid >> 5, pcol = tid & 31;
        jjg = cg * 32 + pcol;
        gb  = r * 8 + pb;
        uid = Ui_w[(size_t)jjg * HH + jjg];
        ufd = Uf_w[(size_t)jjg * HH + jjg];
        ugd = Ug_w[(size_t)jjg * HH + jjg];
    }
    // prime xps[0] (drain waves)
    if (w >= 4) {
        const int a = w - 4, b8 = lane >> 3, cq = lane & 7;
        const float* src = (a == 0) ? b_i : (a == 1) ? b_f : (a == 2) ? b_o : b_g;
        const float4 v = *(const float4*)(src + (size_t)(r * 8 + b8) * TT * HH
                                          + cg * 32 + cq * 4);
        *(float4*)&xps[0][a][b8 * 32 + cq * 4] = v;
    }
    __syncthreads();

    for (int t = 0; t < TT; ++t) {
        const int p  = t & 1;
        const int np = p ^ 1;
        const unsigned tg = (unsigned)t & TAGM;

        // ---- speculative tagged clause (8 loads, 2KB/wave); retry on stale ----
        unsigned hv[8];
        const char* hb = (const char*)hpub
                       + ((size_t)(p * 64 + r * 8) * HH + k0 + lane) * 4;
        for (;;) {
            LOADP(hv[0], hv[1], hb);
            LOADP(hv[2], hv[3], hb + 4096);
            LOADP(hv[4], hv[5], hb + 8192);
            LOADP(hv[6], hv[7], hb + 12288);
            asm volatile("s_waitcnt vmcnt(0)" ::: "memory");
            __builtin_amdgcn_sched_barrier(0);
            unsigned bad = 0;
            #pragma unroll
            for (int b = 0; b < 8; ++b) bad |= (hv[b] ^ tg) & TAGM;
            if (__all(bad == 0)) break;
            // fallback: poll the row's single flag line
            const int* fb = &flags[p * (NROW * NCG) + r * NCG];
            for (;;) {
                const int fv = __hip_atomic_load(&fb[lane & 15], __ATOMIC_RELAXED,
                                                 __HIP_MEMORY_SCOPE_AGENT);
                if (__all(fv >= t)) break;
                __builtin_amdgcn_s_sleep(4);
            }
        }

        // stage own slice to LDS (wave-internal broadcast; no cross-wave dep)
        #pragma unroll
        for (int b = 0; b < 8; ++b)
            hlds[w][b][lane] = __uint_as_float(hv[b] & ~TAGM);

        // ---- k-loop: 8 batches x 2 outputs per lane, U in registers ----
        float acc[8][2];
        #pragma unroll
        for (int b = 0; b < 8; ++b) { acc[b][0] = 0.f; acc[b][1] = 0.f; }
        #pragma unroll
        for (int k4 = 0; k4 < 16; ++k4) {
            #pragma unroll
            for (int b = 0; b < 8; ++b) {
                const float4 h4 = *(const float4*)&hlds[w][b][k4 * 4];
                const float2 ua = u2[k4 * 4 + 0];
                const float2 ub2 = u2[k4 * 4 + 1];
                const float2 uc = u2[k4 * 4 + 2];
                const float2 ud = u2[k4 * 4 + 3];
                acc[b][0] = fmaf(h4.x, ua.x,  acc[b][0]);
                acc[b][1] = fmaf(h4.x, ua.y,  acc[b][1]);
                acc[b][0] = fmaf(h4.y, ub2.x, acc[b][0]);
                acc[b][1] = fmaf(h4.y, ub2.y, acc[b][1]);
                acc[b][0] = fmaf(h4.z, uc.x,  acc[b][0]);
                acc[b][1] = fmaf(h4.z, uc.y,  acc[b][1]);
                acc[b][0] = fmaf(h4.w, ud.x,  acc[b][0]);
                acc[b][1] = fmaf(h4.w, ud.y,  acc[b][1]);
            }
        }
        {
            const int colL = lane & 31, g0 = (lane >> 5) << 1;
            #pragma unroll
            for (int b = 0; b < 8; ++b)
                *(float2*)&red[w][(b * 32 + colL) * 4 + g0] =
                    make_float2(acc[b][0], acc[b][1]);
        }
        BARRIER_LGKM();

        // ---- reduce across 8 waves: 2 outputs/thread ----
        {
            float2 s = make_float2(0.f, 0.f);
            #pragma unroll
            for (int ww = 0; ww < 8; ++ww) {
                const float2 v = *(const float2*)&red[ww][tid * 2];
                s.x += v.x; s.y += v.y;
            }
            *(float2*)&pre[tid * 2] = s;
        }
        BARRIER_LGKM();

        if (tid < 256) {
            const float4 p4 = *(const float4*)&pre[tid * 4];
            const float pi = xps[p][0][tid] + p4.x;
            const float pf = xps[p][1][tid] + p4.y;
            const float po = xps[p][2][tid] + p4.z;
            const float pg = xps[p][3][tid] + p4.w;

            const float ig = __fdividef(1.f, 1.f + __expf(-pi));
            const float fg = __fdividef(1.f, 1.f + __expf(-pf));
            const float og = __fdividef(1.f, 1.f + __expf(-po));
            const float tgg = __expf(-2.f * fmaxf(pg, -40.f));
            const float gg = __fdividef(1.f - tgg, 1.f + tgg);

            const float cp = creg;
            const float c  = fg * cp + ig * gg;
            creg = c;
            const float tc = __expf(-2.f * fmaxf(c, -40.f));
            const float th = __fdividef(1.f - tc, 1.f + tc);
            const float h  = og * th;
            const float e  = og * (1.f - th * th);
            const float cd = cp * (fg * (1.f - fg)) * ufd
                           + ig * (1.f - gg * gg) * ugd
                           + gg * (ig * (1.f - ig)) * uid;

            // publish tagged h — no drain; tags are the truth
            const unsigned pk = (__float_as_uint(h) & ~TAGM)
                              | ((unsigned)(t + 1) & TAGM);
            unsigned* dp = hpub + ((size_t)np * 64 + gb) * HH + jjg;
            asm volatile("global_store_dword %0, %1, off sc0 sc1"
                         :: "v"(dp), "v"(pk) : "memory");
            if (tid == 0)
                __hip_atomic_store(&flags[np * (NROW * NCG) + r * NCG + cg], t + 1,
                                   __ATOMIC_RELAXED, __HIP_MEMORY_SCOPE_AGENT);

            shout[p][0][tid] = h;
            shout[p][1][tid] = fg;
            shout[p][2][tid] = e;
            shout[p][3][tid] = cd;
        } else {
            const int a = w - 4, b8 = lane >> 3, cq = lane & 7;
            float* dstb = (a == 0) ? b_i : (a == 1) ? b_f : (a == 2) ? b_o : b_g;
            if (t > 0) {
                const float4 v = *(const float4*)&shout[np][a][b8 * 32 + cq * 4];
                *(float4*)(dstb + ((size_t)(r * 8 + b8) * TT + (t - 1)) * HH
                           + cg * 32 + cq * 4) = v;
            }
            if (t + 1 < TT) {
                const float4 v = *(const float4*)(dstb
                    + ((size_t)(r * 8 + b8) * TT + (t + 1)) * HH + cg * 32 + cq * 4);
                *(float4*)&xps[np][a][b8 * 32 + cq * 4] = v;
            }
        }
    }

    // drain final step's outputs (t = TT-1, parity 1)
    __syncthreads();
    if (w >= 4) {
        const int a = w - 4, b8 = lane >> 3, cq = lane & 7;
        float* dstb = (a == 0) ? b_i : (a == 1) ? b_f : (a == 2) ? b_o : b_g;
        const float4 v = *(const float4*)&shout[1][a][b8 * 32 + cq * 4];
        *(float4*)(dstb + ((size_t)(r * 8 + b8) * TT + (TT - 1)) * HH
                   + cg * 32 + cq * 4) = v;
    }
}

// ys[r] = dot(hs[r,:], out_w) + out_b ; one wave per row r = b*T + t
__global__ __launch_bounds__(256) void lstm_y(
    const float* __restrict__ hs, const float* __restrict__ out_w,
    const float* __restrict__ out_b, float* __restrict__ ys)
{
    const int wave = threadIdx.x >> 6;
    const int lane = threadIdx.x & 63;
    const int rr = blockIdx.x * 4 + wave;

    const float4* hv = (const float4*)(hs + (size_t)rr * HH);
    const float4* wv = (const float4*)out_w;
    float acc = 0.f;
    #pragma unroll
    for (int i = 0; i < 2; ++i) {
        float4 h4 = hv[lane * 2 + i];
        float4 w4 = wv[lane * 2 + i];
        acc += h4.x * w4.x + h4.y * w4.y + h4.z * w4.z + h4.w * w4.w;
    }
    #pragma unroll
    for (int m = 32; m >= 1; m >>= 1) acc += __shfl_xor(acc, m, 64);
    if (lane == 0) ys[rr] = acc + out_b[0];
}

extern "C" void kernel_launch(void* const* d_in, const int* in_sizes, int n_in,
                              void* d_out, int out_size, void* d_ws, size_t ws_size,
                              hipStream_t stream)
{
    const float* x    = (const float*)d_in[0];
    const float* Wi_w = (const float*)d_in[1];
    const float* Wi_b = (const float*)d_in[2];
    const float* Ui_w = (const float*)d_in[3];
    const float* Wf_w = (const float*)d_in[4];
    const float* Wf_b = (const float*)d_in[5];
    const float* Uf_w = (const float*)d_in[6];
    const float* Wo_w = (const float*)d_in[7];
    const float* Wo_b = (const float*)d_in[8];
    const float* Uo_w = (const float*)d_in[9];
    const float* Wg_w = (const float*)d_in[10];
    const float* Wg_b = (const float*)d_in[11];
    const float* Ug_w = (const float*)d_in[12];
    const float* out_w = (const float*)d_in[13];
    const float* out_b = (const float*)d_in[14];

    float* ys  = (float*)d_out;                     // [B*T]
    float* hs  = ys + (size_t)BB * TT;              // [B*T*H]
    float* fs  = hs + (size_t)BB * TT * HH;
    float* es  = fs + (size_t)BB * TT * HH;
    float* cds = es + (size_t)BB * TT * HH;

    // ws layout: [hpub 256KB][flags 1KB][utT2 4MB]
    unsigned* hpub  = (unsigned*)d_ws;
    int*      flags = (int*)(hpub + (size_t)2 * BB * HH);
    float*    utT2  = (float*)(flags + 2 * NROW * NCG);

    // zero hpub (tag 0 = gen 0, h = 0) + flags every call (graph-replay safe)
    hipMemsetAsync(d_ws, 0,
                   (size_t)2 * BB * HH * sizeof(unsigned)
                   + (size_t)2 * NROW * NCG * sizeof(int), stream);

    uT2_kernel<<<NCG, 256, 0, stream>>>(Ui_w, Uf_w, Uo_w, Ug_w, utT2);

    xproj_kernel<<<256, 512, 0, stream>>>(x, Wi_w, Wi_b, Wf_w, Wf_b,
                                          Wo_w, Wo_b, Wg_w, Wg_b,
                                          hs, fs, es, cds);

    lstm_persist<<<NWG, 512, 0, stream>>>(utT2, Ui_w, Uf_w, Ug_w,
                                          hs, fs, es, cds, hpub, flags);

    lstm_y<<<(BB * TT) / 4, 256, 0, stream>>>(hs, out_w, out_b, ys);
}

// Round 12
// 3153.737 us; speedup vs baseline: 2.2711x; 1.1684x over previous
//
#include <hip/hip_runtime.h>
#include <math.h>

#define BB 64
#define TT 512
#define DD 128
#define HH 512
#define NROW 16
#define NCG 16
#define NWG 256
#define TAGM 511u

// 2 agent-coherent 4B loads, stride 2048B (13-bit signed imm max 4095!).
#define LOADB2(d0,d1, ptr)                                                    \
  asm volatile("global_load_dword %0, %2, off sc0 sc1\n\t"                    \
               "global_load_dword %1, %2, off offset:2048 sc0 sc1"            \
               : "=v"(d0), "=v"(d1) : "v"(ptr) : "memory")

// WG barrier ordering LDS only — global stores stay in flight across steps.
#define BARRIER_LGKM() asm volatile("s_waitcnt lgkmcnt(0)\n\ts_barrier" ::: "memory")

// ---------------------------------------------------------------------------
// Pre-kernel: utT2[cg][k][128], inner ii = 2*lane + d -> U_g[cg*32+(lane&31)][k],
// g = (lane>>5)*2 + d. Feeds register-resident per-lane U (float2 per k).
// ---------------------------------------------------------------------------
__global__ __launch_bounds__(256) void uT2_kernel(
    const float* __restrict__ Ui_w, const float* __restrict__ Uf_w,
    const float* __restrict__ Uo_w, const float* __restrict__ Ug_w,
    float* __restrict__ utT2)
{
    const int cg = blockIdx.x;
    for (int idx = threadIdx.x; idx < HH * 128; idx += 256) {
        const int k = idx >> 7, ii = idx & 127;
        const int l = ii >> 1, d = ii & 1;
        const int j = cg * 32 + (l & 31);
        const int g = ((l >> 5) << 1) + d;
        const float* U = (g == 0) ? Ui_w : (g == 1) ? Uf_w : (g == 2) ? Uo_w : Ug_w;
        utT2[((size_t)cg * HH + k) * 128 + ii] = U[(size_t)j * HH + k];
    }
}

// ---------------------------------------------------------------------------
// Persistent kernel. 256 WGs: row r = wg&15 (4 batches), cg = wg>>4 (32 cols).
// 8 waves, k-slice 64/wave, U register-resident. One lgkm barrier per step.
// Roles after barrier: waves 0-1 pointwise+publish; waves 2-3 drain outputs;
// waves 4-7 compute xp(t+1) (xproj fused, W register-resident); wave 4 also
// stages x(t+2) to LDS. h exchange: mantissa-tagged (9 LSB = gen mod 512)
// sc0/sc1 stores, spec clause + row-flag-hint fallback. No drains anywhere.
// ---------------------------------------------------------------------------
__global__ __launch_bounds__(512, 2) void lstm_persist(
    const float* __restrict__ utT2,
    const float* __restrict__ Ui_w, const float* __restrict__ Uf_w,
    const float* __restrict__ Ug_w,
    const float* __restrict__ x,
    const float* __restrict__ Wi_w, const float* __restrict__ Wi_b,
    const float* __restrict__ Wf_w, const float* __restrict__ Wf_b,
    const float* __restrict__ Wo_w, const float* __restrict__ Wo_b,
    const float* __restrict__ Wg_w, const float* __restrict__ Wg_b,
    float* __restrict__ b_i, float* __restrict__ b_f,
    float* __restrict__ b_o, float* __restrict__ b_g,
    unsigned* __restrict__ hpub,   // [2][64][512] tagged f32
    int* __restrict__ flags)       // [2][16][16]
{
    __shared__ float  hlds[8][4][64];         //  8 KB own-wave h slice
    __shared__ float2 red2[2][8][2][128];     // 32 KB partials (parity dbuf)
    __shared__ float  xps[2][4][128];         //  4 KB xp (parity dbuf)
    __shared__ float  shout[2][4][128];       //  4 KB outputs (parity dbuf)
    __shared__ float  xlds[2][4][128];        //  4 KB x rows (parity dbuf)

    const int tid  = threadIdx.x;
    const int w    = tid >> 6;
    const int lane = tid & 63;
    const int wg   = blockIdx.x;
    const int r    = wg & 15;
    const int cg   = wg >> 4;
    const int k0   = w << 6;

    // register-resident U slice: lane owns (col=lane&31, gates gp*2, gp*2+1)
    float2 u2[64];
    {
        const float* ub = utT2 + ((size_t)cg * HH + k0) * 128 + 2 * lane;
        #pragma unroll
        for (int k = 0; k < 64; ++k) u2[k] = *(const float2*)(ub + (size_t)k * 128);
    }

    // pointwise state (threads 0..127): b = tid>>5, col = tid&31
    float creg = 0.f, uid = 0.f, ufd = 0.f, ugd = 0.f;
    int jjg = 0, gb = 0;
    if (tid < 128) {
        jjg = cg * 32 + (tid & 31);
        gb  = r * 4 + (tid >> 5);
        uid = Ui_w[(size_t)jjg * HH + jjg];
        ufd = Uf_w[(size_t)jjg * HH + jjg];
        ugd = Ug_w[(size_t)jjg * HH + jjg];
    }

    // xproj registers (waves 4-7): gate ga = w-4, col = lane&31, dh = lane>>5
    float4 wreg[16];
    float  wbias = 0.f;
    const int ga = (w >= 4) ? (w - 4) : 0;
    if (w >= 4) {
        const int col = lane & 31, dh = lane >> 5;
        const float* Ws = (ga == 0) ? Wi_w : (ga == 1) ? Wf_w : (ga == 2) ? Wo_w : Wg_w;
        const float* Bs = (ga == 0) ? Wi_b : (ga == 1) ? Wf_b : (ga == 2) ? Wo_b : Wg_b;
        const float* base = Ws + (size_t)(cg * 32 + col) * DD + dh * 64;
        #pragma unroll
        for (int k4 = 0; k4 < 16; ++k4) wreg[k4] = *(const float4*)(base + k4 * 4);
        wbias = Bs[cg * 32 + col];
    }

    // ---- prime: stage x(0),x(1); compute xp(0) -> xps[0] ----
    if (w == 4) {
        const int bx = lane >> 4, c8 = lane & 15;
        #pragma unroll
        for (int u = 0; u < 2; ++u) {
            const float* xs = x + ((size_t)(r * 4 + bx) * TT + u) * DD + c8 * 8;
            *(float4*)&xlds[u][bx][c8 * 8]     = *(const float4*)(xs);
            *(float4*)&xlds[u][bx][c8 * 8 + 4] = *(const float4*)(xs + 4);
        }
    }
    __syncthreads();
    if (w >= 4) {
        const int col = lane & 31, dh = lane >> 5;
        #pragma unroll
        for (int b = 0; b < 4; ++b) {
            float a = 0.f;
            #pragma unroll
            for (int k4 = 0; k4 < 16; ++k4) {
                const float4 xv = *(const float4*)&xlds[0][b][dh * 64 + k4 * 4];
                const float4 ww = wreg[k4];
                a = fmaf(xv.x, ww.x, a); a = fmaf(xv.y, ww.y, a);
                a = fmaf(xv.z, ww.z, a); a = fmaf(xv.w, ww.w, a);
            }
            const float full = a + __shfl_xor(a, 32);
            if (lane < 32) xps[0][ga][b * 32 + col] = full + wbias;
        }
    }
    __syncthreads();

    for (int t = 0; t < TT; ++t) {
        const int p  = t & 1;
        const int np = p ^ 1;
        const unsigned tg = (unsigned)t & TAGM;

        // ---- speculative tagged clause (4 loads, 1KB/wave); retry on stale ----
        unsigned hv[4];
        const char* hb = (const char*)hpub
                       + ((size_t)(p * 64 + r * 4) * HH + k0 + lane) * 4;
        for (;;) {
            LOADB2(hv[0], hv[1], hb);
            LOADB2(hv[2], hv[3], hb + 4096);
            asm volatile("s_waitcnt vmcnt(0)" ::: "memory");
            __builtin_amdgcn_sched_barrier(0);
            unsigned bad = 0;
            #pragma unroll
            for (int b = 0; b < 4; ++b) bad |= (hv[b] ^ tg) & TAGM;
            if (__all(bad == 0)) break;
            // fallback: poll the row's flag line (16 ints = 1 line)
            const int* fb = &flags[p * (NROW * NCG) + r * NCG];
            for (;;) {
                const int fv = __hip_atomic_load(&fb[lane & 15], __ATOMIC_RELAXED,
                                                 __HIP_MEMORY_SCOPE_AGENT);
                if (__all(fv >= t)) break;
                __builtin_amdgcn_s_sleep(2);
            }
        }

        // stage own slice (wave-local; no barrier needed before k-loop)
        #pragma unroll
        for (int b = 0; b < 4; ++b)
            hlds[w][b][lane] = __uint_as_float(hv[b] & ~TAGM);

        // ---- k-loop: 4 batches x 2 outputs per lane, U in registers ----
        float acc[4][2];
        #pragma unroll
        for (int b = 0; b < 4; ++b) { acc[b][0] = 0.f; acc[b][1] = 0.f; }
        #pragma unroll
        for (int k4 = 0; k4 < 16; ++k4) {
            #pragma unroll
            for (int b = 0; b < 4; ++b) {
                const float4 h4 = *(const float4*)&hlds[w][b][k4 * 4];
                const float2 ua = u2[k4 * 4 + 0];
                const float2 ub = u2[k4 * 4 + 1];
                const float2 uc = u2[k4 * 4 + 2];
                const float2 ud = u2[k4 * 4 + 3];
                acc[b][0] = fmaf(h4.x, ua.x, acc[b][0]);
                acc[b][1] = fmaf(h4.x, ua.y, acc[b][1]);
                acc[b][0] = fmaf(h4.y, ub.x, acc[b][0]);
                acc[b][1] = fmaf(h4.y, ub.y, acc[b][1]);
                acc[b][0] = fmaf(h4.z, uc.x, acc[b][0]);
                acc[b][1] = fmaf(h4.z, uc.y, acc[b][1]);
                acc[b][0] = fmaf(h4.w, ud.x, acc[b][0]);
                acc[b][1] = fmaf(h4.w, ud.y, acc[b][1]);
            }
        }
        {
            const int col = lane & 31, gp = lane >> 5;
            #pragma unroll
            for (int b = 0; b < 4; ++b)
                red2[p][w][gp][b * 32 + col] = make_float2(acc[b][0], acc[b][1]);
        }
        BARRIER_LGKM();   // the single per-step barrier

        if (w < 2) {
            // ---- fused reduce + pointwise + publish (tid < 128) ----
            float s0 = 0.f, s1 = 0.f, s2 = 0.f, s3 = 0.f;
            #pragma unroll
            for (int ww = 0; ww < 8; ++ww) {
                const float2 a = red2[p][ww][0][tid];
                const float2 b = red2[p][ww][1][tid];
                s0 += a.x; s1 += a.y; s2 += b.x; s3 += b.y;
            }
            const float pi = xps[p][0][tid] + s0;
            const float pf = xps[p][1][tid] + s1;
            const float po = xps[p][2][tid] + s2;
            const float pg = xps[p][3][tid] + s3;

            const float ig = __fdividef(1.f, 1.f + __expf(-pi));
            const float fg = __fdividef(1.f, 1.f + __expf(-pf));
            const float og = __fdividef(1.f, 1.f + __expf(-po));
            const float tgg = __expf(-2.f * fmaxf(pg, -40.f));
            const float gg = __fdividef(1.f - tgg, 1.f + tgg);

            const float cp = creg;
            const float c  = fg * cp + ig * gg;
            creg = c;
            const float tc = __expf(-2.f * fmaxf(c, -40.f));
            const float th = __fdividef(1.f - tc, 1.f + tc);
            const float h  = og * th;
            const float e  = og * (1.f - th * th);
            const float cd = cp * (fg * (1.f - fg)) * ufd
                           + ig * (1.f - gg * gg) * ugd
                           + gg * (ig * (1.f - ig)) * uid;

            // publish tagged h — no drain; tags are the truth
            const unsigned pk = (__float_as_uint(h) & ~TAGM)
                              | ((unsigned)(t + 1) & TAGM);
            unsigned* dp = hpub + ((size_t)np * 64 + gb) * HH + jjg;
            asm volatile("global_store_dword %0, %1, off sc0 sc1"
                         :: "v"(dp), "v"(pk) : "memory");
            if (tid == 0)
                __hip_atomic_store(&flags[np * (NROW * NCG) + r * NCG + cg], t + 1,
                                   __ATOMIC_RELAXED, __HIP_MEMORY_SCOPE_AGENT);

            shout[p][0][tid] = h;
            shout[p][1][tid] = fg;
            shout[p][2][tid] = e;
            shout[p][3][tid] = cd;
        } else if (w < 4) {
            // ---- drain gen t-1 outputs (waves 2-3, 2 arrays each) ----
            if (t > 0) {
                const int a2  = ((w - 2) << 1) | (lane >> 5);
                const int i32 = lane & 31;
                float* dstb = (a2 == 0) ? b_i : (a2 == 1) ? b_f
                            : (a2 == 2) ? b_o : b_g;
                const float4 v = *(const float4*)&shout[np][a2][i32 * 4];
                *(float4*)(dstb + ((size_t)(r * 4 + (i32 >> 3)) * TT + (t - 1)) * HH
                           + cg * 32 + (i32 & 7) * 4) = v;
            }
        } else {
            // ---- xproj: xp(t+1) -> xps[np] (waves 4-7); w4 stages x(t+2) ----
            if (t + 1 < TT) {
                const int col = lane & 31, dh = lane >> 5;
                #pragma unroll
                for (int b = 0; b < 4; ++b) {
                    float a = 0.f;
                    #pragma unroll
                    for (int k4 = 0; k4 < 16; ++k4) {
                        const float4 xv = *(const float4*)&xlds[np][b][dh * 64 + k4 * 4];
                        const float4 ww = wreg[k4];
                        a = fmaf(xv.x, ww.x, a); a = fmaf(xv.y, ww.y, a);
                        a = fmaf(xv.z, ww.z, a); a = fmaf(xv.w, ww.w, a);
                    }
                    const float full = a + __shfl_xor(a, 32);
                    if (lane < 32) xps[np][ga][b * 32 + col] = full + wbias;
                }
            }
            if (w == 4 && t + 2 < TT) {
                const int bx = lane >> 4, c8 = lane & 15;
                const float* xs = x + ((size_t)(r * 4 + bx) * TT + (t + 2)) * DD + c8 * 8;
                *(float4*)&xlds[p][bx][c8 * 8]     = *(const float4*)(xs);
                *(float4*)&xlds[p][bx][c8 * 8 + 4] = *(const float4*)(xs + 4);
            }
        }
    }

    // drain final step's outputs (t = TT-1, parity 1)
    __syncthreads();
    if (w == 2 || w == 3) {
        const int a2  = ((w - 2) << 1) | (lane >> 5);
        const int i32 = lane & 31;
        float* dstb = (a2 == 0) ? b_i : (a2 == 1) ? b_f : (a2 == 2) ? b_o : b_g;
        const float4 v = *(const float4*)&shout[1][a2][i32 * 4];
        *(float4*)(dstb + ((size_t)(r * 4 + (i32 >> 3)) * TT + (TT - 1)) * HH
                   + cg * 32 + (i32 & 7) * 4) = v;
    }
}

// ys[r] = dot(hs[r,:], out_w) + out_b ; one wave per row r = b*T + t
__global__ __launch_bounds__(256) void lstm_y(
    const float* __restrict__ hs, const float* __restrict__ out_w,
    const float* __restrict__ out_b, float* __restrict__ ys)
{
    const int wave = threadIdx.x >> 6;
    const int lane = threadIdx.x & 63;
    const int rr = blockIdx.x * 4 + wave;

    const float4* hv = (const float4*)(hs + (size_t)rr * HH);
    const float4* wv = (const float4*)out_w;
    float acc = 0.f;
    #pragma unroll
    for (int i = 0; i < 2; ++i) {
        float4 h4 = hv[lane * 2 + i];
        float4 w4 = wv[lane * 2 + i];
        acc += h4.x * w4.x + h4.y * w4.y + h4.z * w4.z + h4.w * w4.w;
    }
    #pragma unroll
    for (int m = 32; m >= 1; m >>= 1) acc += __shfl_xor(acc, m, 64);
    if (lane == 0) ys[rr] = acc + out_b[0];
}

extern "C" void kernel_launch(void* const* d_in, const int* in_sizes, int n_in,
                              void* d_out, int out_size, void* d_ws, size_t ws_size,
                              hipStream_t stream)
{
    const float* x    = (const float*)d_in[0];
    const float* Wi_w = (const float*)d_in[1];
    const float* Wi_b = (const float*)d_in[2];
    const float* Ui_w = (const float*)d_in[3];
    const float* Wf_w = (const float*)d_in[4];
    const float* Wf_b = (const float*)d_in[5];
    const float* Uf_w = (const float*)d_in[6];
    const float* Wo_w = (const float*)d_in[7];
    const float* Wo_b = (const float*)d_in[8];
    const float* Uo_w = (const float*)d_in[9];
    const float* Wg_w = (const float*)d_in[10];
    const float* Wg_b = (const float*)d_in[11];
    const float* Ug_w = (const float*)d_in[12];
    const float* out_w = (const float*)d_in[13];
    const float* out_b = (const float*)d_in[14];

    float* ys  = (float*)d_out;                     // [B*T]
    float* hs  = ys + (size_t)BB * TT;              // [B*T*H]
    float* fs  = hs + (size_t)BB * TT * HH;
    float* es  = fs + (size_t)BB * TT * HH;
    float* cds = es + (size_t)BB * TT * HH;

    // ws layout: [hpub 256KB][flags 2KB][utT2 4MB]
    unsigned* hpub  = (unsigned*)d_ws;
    int*      flags = (int*)(hpub + (size_t)2 * BB * HH);
    float*    utT2  = (float*)(flags + 2 * NROW * NCG);

    // zero hpub (tag 0 = gen 0, h = 0) + flags every call (graph-replay safe)
    hipMemsetAsync(d_ws, 0,
                   (size_t)2 * BB * HH * sizeof(unsigned)
                   + (size_t)2 * NROW * NCG * sizeof(int), stream);

    uT2_kernel<<<NCG, 256, 0, stream>>>(Ui_w, Uf_w, Uo_w, Ug_w, utT2);

    lstm_persist<<<NWG, 512, 0, stream>>>(utT2, Ui_w, Uf_w, Ug_w,
                                          x, Wi_w, Wi_b, Wf_w, Wf_b,
                                          Wo_w, Wo_b, Wg_w, Wg_b,
                                          hs, fs, es, cds, hpub, flags);

    lstm_y<<<(BB * TT) / 4, 256, 0, stream>>>(hs, out_w, out_b, ys);
}